// Round 2
// baseline (439.910 us; speedup 1.0000x reference)
//
#include <hip/hip_runtime.h>
#include <hip/hip_bf16.h>

// GraphConvolutionLayer on MI355X (gfx950)
//   scale = 1/(rowsum(adj)+beta);  agg = adj@x + beta*x;  out = (scale*agg)@W + bias
// Design:
//   k1: tile/convert x (8192x256) and W (256x256) fp32 -> bf16 in MFMA-B tiled
//       layout [kblk][n16][kg][nl][8] => contiguous global_load_lds staging AND
//       conflict-free b128 B-fragment reads.
//   k2 (stage1): agg partials = adj@x, bf16 MFMA 16x16x32. Block = 256 thr (4 waves),
//       C-tile 64(M) x 256(N full, so adj streams from HBM exactly once), K-split KS.
//       A-tile (64x32 fp32, 8 KB) via global_load_lds w/ XOR src-lane swizzle
//       (frag reads land conflict-free). rowsum fused from wave0's A-frags.
//   k3 (stage2): out = (scale*(sum partials + beta*x)) @ W + bias, same MFMA skeleton.

typedef __attribute__((ext_vector_type(8))) short  short8;
typedef __attribute__((ext_vector_type(4))) float  floatx4;

#define N_NODES 8192
#define F_DIM   256

#define ASYNC16(g, l)                                                          \
  __builtin_amdgcn_global_load_lds(                                           \
      (const __attribute__((address_space(1))) void*)(g),                     \
      (__attribute__((address_space(3))) void*)(l), 16, 0, 0)

// fp32 -> bf16 round-to-nearest-even (no NaN handling; inputs are finite)
__device__ __forceinline__ unsigned short f2bf(float f) {
  unsigned u = __float_as_uint(f);
  return (unsigned short)((u + 0x7FFFu + ((u >> 16) & 1u)) >> 16);
}

__device__ __forceinline__ short8 pack_bf16x8(floatx4 a, floatx4 b) {
  short8 r;
  r[0] = (short)f2bf(a.x);
  r[1] = (short)f2bf(a.y);
  r[2] = (short)f2bf(a.z);
  r[3] = (short)f2bf(a.w);
  r[4] = (short)f2bf(b.x);
  r[5] = (short)f2bf(b.y);
  r[6] = (short)f2bf(b.z);
  r[7] = (short)f2bf(b.w);
  return r;
}

// ---------------------------------------------------------------------------
// k1: fp32 [K][256] -> bf16 tiled [K/32][n16(16)][kg(4)][nl(16)][8]
// grid: K*256/8/256 blocks of 256 threads (exact)
// ---------------------------------------------------------------------------
__global__ __launch_bounds__(256) void tile_bf16_kernel(
    const float* __restrict__ src, unsigned short* __restrict__ dst, int K) {
  const int Nn = F_DIM;
  int cid = blockIdx.x * 256 + threadIdx.x;      // one 8-element chunk
  int per_kblk = Nn * 4;                         // 1024 chunks per 32-k block
  int kblk = cid / per_kblk;
  int rem  = cid - kblk * per_kblk;
  int n16 = rem >> 6;
  int kg  = (rem >> 4) & 3;
  int nl  = rem & 15;
  int n = n16 * 16 + nl;
  int k = kblk * 32 + kg * 8;
  const float* s = src + (size_t)k * Nn + n;
  floatx4 v0, v1;
  v0.x = s[0];
  v0.y = s[(size_t)Nn];
  v0.z = s[(size_t)2 * Nn];
  v0.w = s[(size_t)3 * Nn];
  v1.x = s[(size_t)4 * Nn];
  v1.y = s[(size_t)5 * Nn];
  v1.z = s[(size_t)6 * Nn];
  v1.w = s[(size_t)7 * Nn];
  *(short8*)(dst + (size_t)cid * 8) = pack_bf16x8(v0, v1);
}

// ---------------------------------------------------------------------------
// k2: stage1 — partial agg (adj @ x) + partial rowsums, K-split KS
// grid: dim3(128, KS), block 256
// ---------------------------------------------------------------------------
template <int KS>
__global__ __launch_bounds__(256, 2) void stage1_kernel(
    const float* __restrict__ adj, const unsigned short* __restrict__ xbt,
    float* __restrict__ part, float* __restrict__ rsp) {
  __shared__ float         At[64 * 32];     // 8 KB fp32, [row][grp^(row&7)]
  __shared__ unsigned short Bt[32 * F_DIM]; // 16 KB bf16 tiled

  const int tid = threadIdx.x;
  const int w  = tid >> 6;
  const int l  = tid & 63;
  const int kq = l >> 4;       // MFMA k-quad
  const int ml = l & 15;
  const int m0 = blockIdx.x * 64;
  const int ks = blockIdx.y;
  const int kbeg   = ks * (N_NODES / KS);
  const int KSTEPS = (N_NODES / KS) / 32;

  // A staging: wave w covers chunks 2w,2w+1 (8 rows each). lane: row=c*8+l/8,
  // source col-group XOR-swizzled so frag reads are ~conflict-free.
  const int arow = w * 16 + (l >> 3);
  const int srcg = (l & 7) ^ ((l >> 3) & 7);
  const float* agp0 = adj + (size_t)(m0 + arow) * N_NODES + kbeg + srcg * 4;
  const float* agp1 = agp0 + (size_t)8 * N_NODES;
  float* aldst0 = At + (w * 2) * 256;
  float* aldst1 = At + (w * 2 + 1) * 256;
  // B staging: 16 KB contiguous per k-block; wave w covers chunks 4w..4w+3
  const unsigned short* bgp =
      xbt + (size_t)(kbeg / 32) * (32 * F_DIM) + (w * 4) * 512 + l * 8;
  unsigned short* bldst = Bt + (w * 4) * 512;

  int aoff0[4], aoff1[4], boff[4];
#pragma unroll
  for (int mf = 0; mf < 4; ++mf) {
    int m = mf * 16 + ml;
    aoff0[mf] = m * 32 + (((kq * 2)     ^ (m & 7)) * 4);
    aoff1[mf] = m * 32 + (((kq * 2 + 1) ^ (m & 7)) * 4);
  }
#pragma unroll
  for (int nf = 0; nf < 4; ++nf)
    boff[nf] = (w * 4 + nf) * 512 + kq * 128 + ml * 8;

  floatx4 acc[4][4];
  const floatx4 zf4 = {0.f, 0.f, 0.f, 0.f};
#pragma unroll
  for (int mf = 0; mf < 4; ++mf)
#pragma unroll
    for (int nf = 0; nf < 4; ++nf) acc[mf][nf] = zf4;
  float rsum[4] = {0.f, 0.f, 0.f, 0.f};

  for (int s = 0; s < KSTEPS; ++s) {
    ASYNC16(agp0, aldst0);
    ASYNC16(agp1, aldst1);
    ASYNC16(bgp,         bldst);
    ASYNC16(bgp +  512,  bldst +  512);
    ASYNC16(bgp + 1024,  bldst + 1024);
    ASYNC16(bgp + 1536,  bldst + 1536);
    agp0 += 32; agp1 += 32; bgp += 32 * F_DIM;
    __syncthreads();   // drains vmcnt -> tiles ready

    short8 af[4];
#pragma unroll
    for (int mf = 0; mf < 4; ++mf) {
      floatx4 a0 = *(const floatx4*)(At + aoff0[mf]);
      floatx4 a1 = *(const floatx4*)(At + aoff1[mf]);
      if (w == 0)   // fused rowsum: wave0 already reads the whole A-tile
        rsum[mf] += (a0.x + a0.y + a0.z + a0.w) + (a1.x + a1.y + a1.z + a1.w);
      af[mf] = pack_bf16x8(a0, a1);
    }
#pragma unroll
    for (int nf = 0; nf < 4; ++nf) {
      short8 bv = *(const short8*)(Bt + boff[nf]);
#pragma unroll
      for (int mf = 0; mf < 4; ++mf)
        acc[mf][nf] =
            __builtin_amdgcn_mfma_f32_16x16x32_bf16(af[mf], bv, acc[mf][nf], 0, 0, 0);
    }
    __syncthreads();   // all waves done reading before next overwrite
  }

  // epilogue: C/D layout col=lane&15, row=quad*4+reg (m89-verified)
  float* pout = part + (size_t)ks * N_NODES * F_DIM;
#pragma unroll
  for (int mf = 0; mf < 4; ++mf)
#pragma unroll
    for (int nf = 0; nf < 4; ++nf) {
      int col = w * 64 + nf * 16 + ml;
#pragma unroll
      for (int r = 0; r < 4; ++r) {
        int row = m0 + mf * 16 + kq * 4 + r;
        pout[(size_t)row * F_DIM + col] = acc[mf][nf][r];
      }
    }

  if (w == 0) {
#pragma unroll
    for (int mf = 0; mf < 4; ++mf) {
      float v = rsum[mf];
      v += __shfl_xor(v, 16);
      v += __shfl_xor(v, 32);
      if (kq == 0) rsp[ks * N_NODES + m0 + mf * 16 + ml] = v;
    }
  }
}

// ---------------------------------------------------------------------------
// k3: stage2 — out = (scale * (sum partials + beta*x)) @ W + bias
// grid: 256 blocks (32 rows each), block 256
// part may alias out when KS==1 (block only rewrites rows it alone reads)
// ---------------------------------------------------------------------------
template <int KS>
__global__ __launch_bounds__(256, 2) void stage2_kernel(
    const float* part, const float* __restrict__ rsp,
    const float* __restrict__ x, const float* __restrict__ beta,
    const float* __restrict__ bias, const unsigned short* __restrict__ wbt,
    float* out) {
  __shared__ unsigned short At[32 * 32];     // 2 KB bf16, grp ^ (row&3) swizzle
  __shared__ unsigned short Bt[32 * F_DIM];  // 16 KB
  __shared__ float sscale[32];
  __shared__ float sbeta[32];

  const int tid = threadIdx.x;
  const int w  = tid >> 6;
  const int l  = tid & 63;
  const int kq = l >> 4;
  const int ml = l & 15;
  const int m0 = blockIdx.x * 32;

  if (tid < 32) {
    float rs = 0.f;
#pragma unroll
    for (int p = 0; p < KS; ++p) rs += rsp[p * N_NODES + m0 + tid];
    float b = beta[m0 + tid];
    sbeta[tid]  = b;
    sscale[tid] = 1.0f / (rs + b);
  }
  __syncthreads();

  floatx4 acc[2][4];
  const floatx4 zf4 = {0.f, 0.f, 0.f, 0.f};
#pragma unroll
  for (int mf = 0; mf < 2; ++mf)
#pragma unroll
    for (int nf = 0; nf < 4; ++nf) acc[mf][nf] = zf4;

  const unsigned short* bgp = wbt + (w * 4) * 512 + l * 8;
  unsigned short* bldst = Bt + (w * 4) * 512;

  for (int s = 0; s < 8; ++s) {
    ASYNC16(bgp,        bldst);
    ASYNC16(bgp +  512, bldst +  512);
    ASYNC16(bgp + 1024, bldst + 1024);
    ASYNC16(bgp + 1536, bldst + 1536);
    bgp += 32 * F_DIM;

    if (tid < 128) {  // waves 0-1 build the A-tile (wave-uniform branch)
      int r = tid >> 2, g = tid & 3;
      size_t off = (size_t)(m0 + r) * F_DIM + s * 32 + g * 8;
      floatx4 v0 = *(const floatx4*)(x + off);
      floatx4 v1 = *(const floatx4*)(x + off + 4);
      float bb = sbeta[r];
      v0 *= bb; v1 *= bb;
#pragma unroll
      for (int p = 0; p < KS; ++p) {
        const float* pp = part + (size_t)p * N_NODES * F_DIM + off;
        v0 += *(const floatx4*)pp;
        v1 += *(const floatx4*)(pp + 4);
      }
      float sc = sscale[r];
      v0 *= sc; v1 *= sc;
      *(short8*)(At + r * 32 + ((g ^ (r & 3)) * 8)) = pack_bf16x8(v0, v1);
    }
    __syncthreads();

    short8 af[2];
#pragma unroll
    for (int mf = 0; mf < 2; ++mf) {
      int m = mf * 16 + ml;
      af[mf] = *(const short8*)(At + m * 32 + ((kq ^ (m & 3)) * 8));
    }
#pragma unroll
    for (int nf = 0; nf < 4; ++nf) {
      short8 bv = *(const short8*)(Bt + (w * 4 + nf) * 512 + kq * 128 + ml * 8);
#pragma unroll
      for (int mf = 0; mf < 2; ++mf)
        acc[mf][nf] =
            __builtin_amdgcn_mfma_f32_16x16x32_bf16(af[mf], bv, acc[mf][nf], 0, 0, 0);
    }
    __syncthreads();
  }

#pragma unroll
  for (int nf = 0; nf < 4; ++nf) {
    int col = w * 64 + nf * 16 + ml;
    float bv = bias[col];
#pragma unroll
    for (int mf = 0; mf < 2; ++mf)
#pragma unroll
      for (int r = 0; r < 4; ++r) {
        int row = m0 + mf * 16 + kq * 4 + r;
        out[(size_t)row * F_DIM + col] = acc[mf][nf][r] + bv;
      }
  }
}

// ---------------------------------------------------------------------------
extern "C" void kernel_launch(void* const* d_in, const int* in_sizes, int n_in,
                              void* d_out, int out_size, void* d_ws, size_t ws_size,
                              hipStream_t stream) {
  const float* x    = (const float*)d_in[0];  // [8192][256]
  const float* adj  = (const float*)d_in[1];  // [8192][8192]
  const float* kern = (const float*)d_in[2];  // [256][256]
  const float* bias = (const float*)d_in[3];  // [256]
  const float* beta = (const float*)d_in[4];  // [8192]
  float* out = (float*)d_out;

  char* ws = (char*)d_ws;
  unsigned short* xbt = (unsigned short*)ws;                 // 4 MB
  unsigned short* wbt = xbt + (size_t)N_NODES * F_DIM;       // 128 KB
  float* rsp  = (float*)(wbt + F_DIM * F_DIM);               // 128 KB (KS<=4)
  float* part = (float*)((char*)rsp + 4 * N_NODES * sizeof(float));

  const size_t base    = (size_t)N_NODES * F_DIM * 2 + (size_t)F_DIM * F_DIM * 2 +
                         4 * (size_t)N_NODES * 4;
  const size_t part_sz = (size_t)N_NODES * F_DIM * 4;        // 8 MB per split

  tile_bf16_kernel<<<(N_NODES * F_DIM / 8) / 256, 256, 0, stream>>>(x, xbt, N_NODES);
  tile_bf16_kernel<<<(F_DIM * F_DIM / 8) / 256, 256, 0, stream>>>(kern, wbt, F_DIM);

  if (ws_size >= base + 4 * part_sz) {
    stage1_kernel<4><<<dim3(128, 4), 256, 0, stream>>>(adj, xbt, part, rsp);
    stage2_kernel<4><<<256, 256, 0, stream>>>(part, rsp, x, beta, bias, wbt, out);
  } else if (ws_size >= base + 2 * part_sz) {
    stage1_kernel<2><<<dim3(128, 2), 256, 0, stream>>>(adj, xbt, part, rsp);
    stage2_kernel<2><<<256, 256, 0, stream>>>(part, rsp, x, beta, bias, wbt, out);
  } else {
    // fallback: aggregate lives in d_out; stage2 rewrites it in place (row-local)
    stage1_kernel<1><<<dim3(128, 1), 256, 0, stream>>>(adj, xbt, out, rsp);
    stage2_kernel<1><<<256, 256, 0, stream>>>(out, rsp, x, beta, bias, wbt, out);
  }
}